// Round 9
// baseline (132.189 us; speedup 1.0000x reference)
//
#include <hip/hip_runtime.h>
#include <hip/hip_bf16.h>
#include <stdint.h>

typedef __bf16 bf16_t;
typedef __bf16 bf16x8 __attribute__((ext_vector_type(8)));
typedef float  f32x4  __attribute__((ext_vector_type(4)));

#define DIM    1024
#define NTOK   4096
#define NB     8
#define ROWS   (NB*NTOK)   // 32768
#define QKVC   384
#define INNER  128

// global -> LDS direct copy, 16B per lane (dest = wave-uniform base + lane*16)
#define GLD16(g, l) __builtin_amdgcn_global_load_lds( \
    (const __attribute__((address_space(1))) void*)(g), \
    (__attribute__((address_space(3))) void*)(l), 16, 0, 0)

// workspace offsets (bytes)
#define OFF_WQ    131072u      // 384*1024 bf16   (768 KB)
#define OFF_QKV   1048576u     // 32768*384 bf16  (24 MB)
#define OFF_STATS 26214400u    // 512 chunks * 2304 f32
#define OFF_ATTN  30932992u    // 8*8*16*16 f32
#define OFF_WEFF  30998528u    // 8*1024*128 bf16

// ---------- kernel 0: w_qkv * norm_weight -> bf16 ----------
__global__ __launch_bounds__(256) void k_wconv(const float* __restrict__ wq,
    const float* __restrict__ nw, bf16_t* __restrict__ wqb)
{
    int o = blockIdx.x;            // 384 rows
    int c = threadIdx.x * 4;
    float4 wv = *reinterpret_cast<const float4*>(wq + (size_t)o*DIM + c);
    float4 nv = *reinterpret_cast<const float4*>(nw + c);
    bf16_t* dst = wqb + (size_t)o*DIM + c;
    dst[0]=(bf16_t)(wv.x*nv.x); dst[1]=(bf16_t)(wv.y*nv.y);
    dst[2]=(bf16_t)(wv.z*nv.z); dst[3]=(bf16_t)(wv.w*nv.w);
}

// ---------- kernel 1: FUSED RMSNorm + QKV GEMM ----------
// R8 lesson (MfmaUtil 12.6%, 1 block/CU lockstep): the whole CU idled at every
// barrier drain. Now: tile 64x384, BK=32, 256 thr, grid 512 = 2 blocks/CU ->
// independent barrier domains give implicit drain overlap (m114). LDS 56 KB.
// Swizzle for 64B rows: slot ^= (row>>1)&3 on A-write / B-source / reads
// (uniform 8-per-bank-position = optimal for b128 ops).
__global__ __launch_bounds__(256, 2) void k_qkv_gemm(const float* __restrict__ x,
    const bf16_t* __restrict__ wqb, bf16_t* __restrict__ qkv)
{
    __shared__ bf16_t Al[2][64*32];    // 2 x 4 KB
    __shared__ bf16_t Bl[2][384*32];   // 2 x 24 KB
    __shared__ float srow[64];
    int mt = blockIdx.x;               // 512 blocks = 2/CU
    int row0 = mt*64;
    int t = threadIdx.x;
    int lane = t & 63, lr = lane & 15, lg = lane >> 4;
    int wv = t >> 6;                   // wave 0..3 = N-slice

    // ---- A staging (regs): thread owns row rA (0..63), fp32 elems q*8..q*8+7
    int rA = t >> 2, q = t & 3;
    const float* xrow = x + (size_t)(row0 + rA)*DIM + q*8;
    int wsA = q ^ ((rA >> 1) & 3);     // swizzled write slot (16B units)

    // ---- B staging (global_load_lds): round rd covers rows rd*64+wv*16+(lane>>2)
    int brow  = wv*16 + (lane >> 2);
    int bslot = (lane & 3) ^ ((lane >> 3) & 3);   // pre-swizzled source slot
    const bf16_t* bsrc = wqb + (size_t)brow*DIM + bslot*8;
    int bldsw = wv*512;                // wave-uniform dest base (elems) per round

    int kb = (lg ^ ((lr >> 1) & 3)) * 8;  // read-side physical k-slot (elems)

    float4 u0, u1;                     // 8 fp32 staging regs

#define LOADA(kt) do {                                                   \
        const float4* _xs = reinterpret_cast<const float4*>(xrow + (kt)*32); \
        u0 = _xs[0]; u1 = _xs[1];                                        \
    } while (0)

#define STAGEB(buf, kt) do {                                             \
        _Pragma("unroll")                                                \
        for (int _rd = 0; _rd < 6; _rd++)                                \
            GLD16(bsrc + (size_t)(_rd*64)*DIM + (kt)*32,                 \
                  &Bl[buf][_rd*2048 + bldsw]);                           \
    } while (0)

#define WRITEA(buf) do {                                                 \
        ssq += u0.x*u0.x + u0.y*u0.y + u0.z*u0.z + u0.w*u0.w             \
             + u1.x*u1.x + u1.y*u1.y + u1.z*u1.z + u1.w*u1.w;            \
        bf16x8 v;                                                        \
        v[0]=(bf16_t)u0.x; v[1]=(bf16_t)u0.y; v[2]=(bf16_t)u0.z;         \
        v[3]=(bf16_t)u0.w; v[4]=(bf16_t)u1.x; v[5]=(bf16_t)u1.y;         \
        v[6]=(bf16_t)u1.z; v[7]=(bf16_t)u1.w;                            \
        *reinterpret_cast<bf16x8*>(&Al[buf][rA*32 + wsA*8]) = v;         \
    } while (0)

    float ssq = 0.f;
    f32x4 acc[4][6] = {};

    // prologue: tile 0
    LOADA(0);
    STAGEB(0, 0);
    WRITEA(0);                         // compiler inserts vmcnt wait for A regs
    __syncthreads();                   // drains B GLD16 too

    for (int kt = 0; kt < 32; kt++) {
        int cur = kt & 1;
        if (kt < 31) {
            LOADA(kt + 1);             // issue, no wait
            STAGEB(cur ^ 1, kt + 1);   // fly under MFMAs
        }
        bf16x8 af[4], bfr[6];
        #pragma unroll
        for (int mi = 0; mi < 4; mi++)
            af[mi] = *reinterpret_cast<const bf16x8*>(
                &Al[cur][(mi*16 + lr)*32 + kb]);
        #pragma unroll
        for (int ni = 0; ni < 6; ni++)
            bfr[ni] = *reinterpret_cast<const bf16x8*>(
                &Bl[cur][(wv*96 + ni*16 + lr)*32 + kb]);
        #pragma unroll
        for (int mi = 0; mi < 4; mi++)
            #pragma unroll
            for (int ni = 0; ni < 6; ni++)
                acc[mi][ni] = __builtin_amdgcn_mfma_f32_16x16x32_bf16(
                    af[mi], bfr[ni], acc[mi][ni], 0, 0, 0);
        if (kt < 31) WRITEA(cur ^ 1);  // A regs landed during MFMA phase
        __syncthreads();
    }
#undef LOADA
#undef STAGEB
#undef WRITEA

    // per-row sumsq: 4 consecutive threads share row rA
    ssq += __shfl_xor(ssq, 1, 64);
    ssq += __shfl_xor(ssq, 2, 64);
    if (q == 0) srow[rA] = rsqrtf(ssq*(1.0f/DIM) + 1e-6f);
    __syncthreads();

    #pragma unroll
    for (int mi = 0; mi < 4; mi++)
        #pragma unroll
        for (int ni = 0; ni < 6; ni++) {
            int col_g = wv*96 + ni*16 + lr;
            #pragma unroll
            for (int rr = 0; rr < 4; rr++) {
                int rloc = mi*16 + lg*4 + rr;
                qkv[(size_t)(row0 + rloc)*QKVC + col_g] =
                    (bf16_t)(acc[mi][ni][rr] * srow[rloc]);
            }
        }
}

// ---------- kernel 2: per-(b,chunk) Gram + sumsq partials ----------
__global__ __launch_bounds__(256) void k_stats(const bf16_t* __restrict__ qkv,
    float* __restrict__ stats)
{
    __shared__ bf16_t qk[64*264];   // 64 tokens x 256 (q,k cols) + pad 8
    int bid = blockIdx.x;           // 512 = 8b * 64ch
    int b = bid >> 6, ch = bid & 63;
    int t = threadIdx.x;
    #pragma unroll
    for (int rd = 0; rd < 8; rd++) {
        int tok = (t >> 5) + 8*rd;
        int c8  = (t & 31) * 8;     // cols 0..255 = q,k
        *reinterpret_cast<uint4*>(&qk[tok*264 + c8]) =
            *reinterpret_cast<const uint4*>(
                qkv + ((size_t)b*NTOK + ch*64 + tok)*QKVC + c8);
    }
    __syncthreads();
    int h = t >> 5, s = t & 31, i0 = (s >> 4)*8, j = s & 15;
    float gram[8] = {}, qsq[8] = {}, ksq = 0.f;
    for (int tok = 0; tok < 64; tok++) {
        bf16x8 q8 = *reinterpret_cast<const bf16x8*>(&qk[tok*264 + h*16 + i0]);
        float kf = (float)qk[tok*264 + 128 + h*16 + j];
        ksq += kf*kf;
        #pragma unroll
        for (int m = 0; m < 8; m++) {
            float qf = (float)q8[m];
            gram[m] += qf*kf;
            qsq[m]  += qf*qf;
        }
    }
    float* base = stats + ((size_t)(b*64 + ch)*8 + h)*288;
    #pragma unroll
    for (int m = 0; m < 8; m++) base[(i0 + m)*16 + j] = gram[m];
    if (j == 0) {
        #pragma unroll
        for (int m = 0; m < 8; m++) base[256 + i0 + m] = qsq[m];
    }
    if (s < 16) base[272 + j] = ksq;
}

// ---------- kernel 3: reduce partials, l2-normalize, temperature, softmax ----------
__global__ __launch_bounds__(256) void k_attn(const float* __restrict__ stats,
    const float* __restrict__ temp, float* __restrict__ attn)
{
    int bid = blockIdx.x;           // 64 = 8b * 8h
    int b = bid >> 3, h = bid & 7;
    int t = threadIdx.x, i = t >> 4, j = t & 15;
    float gsum = 0.f, qs = 0.f, ks = 0.f;
    for (int ch = 0; ch < 64; ch++) {
        const float* base = stats + ((size_t)(b*64 + ch)*8 + h)*288;
        gsum += base[i*16 + j];
        qs   += base[256 + i];
        ks   += base[272 + j];
    }
    float et  = expf(temp[h]);
    float sim = gsum * et / (fmaxf(sqrtf(qs), 1e-12f) * fmaxf(sqrtf(ks), 1e-12f));
    float m = sim;
    #pragma unroll
    for (int d = 1; d < 16; d <<= 1) m = fmaxf(m, __shfl_xor(m, d, 16));
    float e = expf(sim - m);
    float ssum = e;
    #pragma unroll
    for (int d = 1; d < 16; d <<= 1) ssum += __shfl_xor(ssum, d, 16);
    attn[((size_t)(b*8 + h)*16 + i)*16 + j] = e / ssum;
}

// ---------- kernel 4: w_eff[b][o][c] = sum_i w_out[o][h*16+i]*attn[b][h][i][j] ----------
__global__ __launch_bounds__(256) void k_weff(const float* __restrict__ attn,
    const float* __restrict__ wout, bf16_t* __restrict__ weff)
{
    __shared__ float at[2048];
    int bid = blockIdx.x;           // 256 = 8b * 32
    int b = bid >> 5, ob = (bid & 31)*32;
    int t = threadIdx.x;
    #pragma unroll
    for (int r = 0; r < 8; r++) at[t + 256*r] = attn[(size_t)b*2048 + t + 256*r];
    __syncthreads();
    int c = t & 127, h = c >> 4, j = c & 15, oo = (t >> 7)*16;
    #pragma unroll
    for (int m = 0; m < 16; m++) {
        int o = ob + oo + m;
        float acc = 0.f;
        #pragma unroll
        for (int i2 = 0; i2 < 16; i2++)
            acc += wout[(size_t)o*INNER + h*16 + i2] * at[(h*16 + i2)*16 + j];
        weff[((size_t)b*DIM + o)*INNER + c] = (bf16_t)acc;
    }
}

// ---------- kernel 5: output GEMM  per b: (4096x128)x(128x1024), fp32 out ----------
__global__ __launch_bounds__(256) void k_out_gemm(const bf16_t* __restrict__ qkv,
    const bf16_t* __restrict__ weff, float* __restrict__ out)
{
    __shared__ bf16_t Al[128*136];
    __shared__ bf16_t Bl[128*136];
    int bid = blockIdx.x;           // 2048 = 8b * 32mt * 8nt
    int b = bid >> 8, rem = bid & 255;
    int mt = rem >> 3, nt = rem & 7;
    int tok0 = mt*128, o0 = nt*128;
    int t = threadIdx.x;
    #pragma unroll
    for (int rd = 0; rd < 8; rd++) {
        int r  = (t >> 4) + 16*rd;
        int c8 = (t & 15) * 8;
        *reinterpret_cast<uint4*>(&Al[r*136 + c8]) =
            *reinterpret_cast<const uint4*>(
                qkv + ((size_t)b*NTOK + tok0 + r)*QKVC + 256 + c8);   // v cols
        *reinterpret_cast<uint4*>(&Bl[r*136 + c8]) =
            *reinterpret_cast<const uint4*>(
                weff + ((size_t)b*DIM + o0 + r)*INNER + c8);
    }
    __syncthreads();
    int w = t >> 6, lane = t & 63, lr = lane & 15, lg = lane >> 4;
    int wr = (w & 1)*64, wc = (w >> 1)*64;
    f32x4 acc[4][4] = {};
    #pragma unroll
    for (int kk = 0; kk < 4; kk++) {
        int kb = kk*32 + lg*8;
        bf16x8 af[4], bfr[4];
        #pragma unroll
        for (int mi = 0; mi < 4; mi++)
            af[mi] = *reinterpret_cast<const bf16x8*>(&Al[(wr + mi*16 + lr)*136 + kb]);
        #pragma unroll
        for (int ni = 0; ni < 4; ni++)
            bfr[ni] = *reinterpret_cast<const bf16x8*>(&Bl[(wc + ni*16 + lr)*136 + kb]);
        #pragma unroll
        for (int mi = 0; mi < 4; mi++)
            #pragma unroll
            for (int ni = 0; ni < 4; ni++)
                acc[mi][ni] = __builtin_amdgcn_mfma_f32_16x16x32_bf16(
                    af[mi], bfr[ni], acc[mi][ni], 0, 0, 0);
    }
    #pragma unroll
    for (int mi = 0; mi < 4; mi++)
        #pragma unroll
        for (int ni = 0; ni < 4; ni++) {
            int col_g = o0 + wc + ni*16 + lr;
            #pragma unroll
            for (int r = 0; r < 4; r++) {
                int row_g = tok0 + wr + mi*16 + lg*4 + r;
                out[((size_t)b*NTOK + row_g)*DIM + col_g] = acc[mi][ni][r];
            }
        }
}

extern "C" void kernel_launch(void* const* d_in, const int* in_sizes, int n_in,
                              void* d_out, int out_size, void* d_ws, size_t ws_size,
                              hipStream_t stream)
{
    const float* x    = (const float*)d_in[0];   // 8*4096*1024
    const float* nw   = (const float*)d_in[1];   // 1024
    const float* wq   = (const float*)d_in[2];   // 384*1024
    const float* temp = (const float*)d_in[3];   // 8
    const float* wout = (const float*)d_in[4];   // 1024*128
    float* out = (float*)d_out;

    char* ws = (char*)d_ws;
    bf16_t* wqb   = (bf16_t*)(ws + OFF_WQ);
    bf16_t* qkv   = (bf16_t*)(ws + OFF_QKV);
    float*  stats = (float*)(ws + OFF_STATS);
    float*  attn  = (float*)(ws + OFF_ATTN);
    bf16_t* weff  = (bf16_t*)(ws + OFF_WEFF);

    k_wconv    <<<384,  256, 0, stream>>>(wq, nw, wqb);
    k_qkv_gemm <<<512,  256, 0, stream>>>(x, wqb, qkv);
    k_stats    <<<512,  256, 0, stream>>>(qkv, stats);
    k_attn     <<<64,   256, 0, stream>>>(stats, temp, attn);
    k_weff     <<<256,  256, 0, stream>>>(attn, wout, weff);
    k_out_gemm <<<2048, 256, 0, stream>>>(qkv, weff, out);
}

// Round 10
// 128.742 us; speedup vs baseline: 1.0268x; 1.0268x over previous
//
#include <hip/hip_runtime.h>
#include <hip/hip_bf16.h>
#include <stdint.h>

typedef __bf16 bf16_t;
typedef __bf16 bf16x8 __attribute__((ext_vector_type(8)));
typedef float  f32x4  __attribute__((ext_vector_type(4)));

#define DIM    1024
#define NTOK   4096
#define NB     8
#define ROWS   (NB*NTOK)   // 32768
#define QKVC   384
#define INNER  128

// global -> LDS direct copy, 16B per lane (dest = wave-uniform base + lane*16)
#define GLD16(g, l) __builtin_amdgcn_global_load_lds( \
    (const __attribute__((address_space(1))) void*)(g), \
    (__attribute__((address_space(3))) void*)(l), 16, 0, 0)

// counted vmcnt: wait until at most n vector-mem ops outstanding (T4)
#define VMCNT(n) asm volatile("s_waitcnt vmcnt(" #n ")" ::: "memory")

// workspace offsets (bytes)
#define OFF_WQ    131072u      // 384*1024 bf16   (768 KB)
#define OFF_QKV   1048576u     // 32768*384 bf16  (24 MB)
#define OFF_STATS 26214400u    // 512 chunks * 2304 f32
#define OFF_ATTN  30932992u    // 8*8*16*16 f32
#define OFF_WEFF  30998528u    // 8*1024*128 bf16

// ---------- kernel 0: w_qkv * norm_weight -> bf16 ----------
__global__ __launch_bounds__(256) void k_wconv(const float* __restrict__ wq,
    const float* __restrict__ nw, bf16_t* __restrict__ wqb)
{
    int o = blockIdx.x;            // 384 rows
    int c = threadIdx.x * 4;
    float4 wv = *reinterpret_cast<const float4*>(wq + (size_t)o*DIM + c);
    float4 nv = *reinterpret_cast<const float4*>(nw + c);
    bf16_t* dst = wqb + (size_t)o*DIM + c;
    dst[0]=(bf16_t)(wv.x*nv.x); dst[1]=(bf16_t)(wv.y*nv.y);
    dst[2]=(bf16_t)(wv.z*nv.z); dst[3]=(bf16_t)(wv.w*nv.w);
}

// ---------- kernel 1: FUSED RMSNorm + QKV GEMM ----------
// R9 lesson: __syncthreads() = vmcnt(0)+barrier -> drains the loads just
// issued for t+1; prefetch never overlapped anything (T4/m218). Now: raw
// s_barrier + counted vmcnt(8) -> tile-t B loads (6 oldest of 14) drain,
// tile-t+1 loads stay in flight across the barrier with a full step to land.
__global__ __launch_bounds__(256, 2) void k_qkv_gemm(const float* __restrict__ x,
    const bf16_t* __restrict__ wqb, bf16_t* __restrict__ qkv)
{
    __shared__ bf16_t Al[2][64*32];    // 2 x 4 KB
    __shared__ bf16_t Bl[2][384*32];   // 2 x 24 KB
    __shared__ float srow[64];
    int mt = blockIdx.x;               // 512 blocks = 2/CU
    int row0 = mt*64;
    int t = threadIdx.x;
    int lane = t & 63, lr = lane & 15, lg = lane >> 4;
    int wv = t >> 6;                   // wave 0..3 = N-slice

    // ---- A staging (regs): thread owns row rA (0..63), fp32 elems q*8..q*8+7
    int rA = t >> 2, q = t & 3;
    const float* xrow = x + (size_t)(row0 + rA)*DIM + q*8;
    int wsA = q ^ ((rA >> 1) & 3);     // swizzled write slot (16B units)

    // ---- B staging (global_load_lds): round rd covers rows rd*64+wv*16+(lane>>2)
    int brow  = wv*16 + (lane >> 2);
    int bslot = (lane & 3) ^ ((lane >> 3) & 3);   // pre-swizzled source slot
    const bf16_t* bsrc = wqb + (size_t)brow*DIM + bslot*8;
    int bldsw = wv*512;                // wave-uniform dest base (elems) per round

    int kb = (lg ^ ((lr >> 1) & 3)) * 8;  // read-side physical k-slot (elems)

    float4 u0, u1;                     // 8 fp32 staging regs

#define LOADA(kt) do {                                                   \
        const float4* _xs = reinterpret_cast<const float4*>(xrow + (kt)*32); \
        u0 = _xs[0]; u1 = _xs[1];                                        \
    } while (0)

#define STAGEB(buf, kt) do {                                             \
        _Pragma("unroll")                                                \
        for (int _rd = 0; _rd < 6; _rd++)                                \
            GLD16(bsrc + (size_t)(_rd*64)*DIM + (kt)*32,                 \
                  &Bl[buf][_rd*2048 + bldsw]);                           \
    } while (0)

#define WRITEA(buf) do {                                                 \
        ssq += u0.x*u0.x + u0.y*u0.y + u0.z*u0.z + u0.w*u0.w             \
             + u1.x*u1.x + u1.y*u1.y + u1.z*u1.z + u1.w*u1.w;            \
        bf16x8 v;                                                        \
        v[0]=(bf16_t)u0.x; v[1]=(bf16_t)u0.y; v[2]=(bf16_t)u0.z;         \
        v[3]=(bf16_t)u0.w; v[4]=(bf16_t)u1.x; v[5]=(bf16_t)u1.y;         \
        v[6]=(bf16_t)u1.z; v[7]=(bf16_t)u1.w;                            \
        *reinterpret_cast<bf16x8*>(&Al[buf][rA*32 + wsA*8]) = v;         \
    } while (0)

    float ssq = 0.f;
    f32x4 acc[4][6] = {};

    // prologue: tile 0 (full drain once)
    LOADA(0);
    STAGEB(0, 0);
    WRITEA(0);
    __syncthreads();

    for (int kt = 0; kt < 32; kt++) {
        int cur = kt & 1;
        if (kt < 31) {
            LOADA(kt + 1);             // +2 vm loads
            STAGEB(cur ^ 1, kt + 1);   // +6 GLD16 -> 14 outstanding
            VMCNT(8);                  // drain B(kt) only; t+1 loads stay in flight
        } else {
            VMCNT(0);                  // last step: drain B(31)
        }
        __builtin_amdgcn_sched_barrier(0);   // rule #18: no hoisting past the wait
        bf16x8 af[4], bfr[6];
        #pragma unroll
        for (int mi = 0; mi < 4; mi++)
            af[mi] = *reinterpret_cast<const bf16x8*>(
                &Al[cur][(mi*16 + lr)*32 + kb]);
        #pragma unroll
        for (int ni = 0; ni < 6; ni++)
            bfr[ni] = *reinterpret_cast<const bf16x8*>(
                &Bl[cur][(wv*96 + ni*16 + lr)*32 + kb]);
        #pragma unroll
        for (int mi = 0; mi < 4; mi++)
            #pragma unroll
            for (int ni = 0; ni < 6; ni++)
                acc[mi][ni] = __builtin_amdgcn_mfma_f32_16x16x32_bf16(
                    af[mi], bfr[ni], acc[mi][ni], 0, 0, 0);
        if (kt < 31) WRITEA(cur ^ 1);  // compiler vmcnt(6) waits A only, post-MFMA
        asm volatile("s_waitcnt lgkmcnt(0)" ::: "memory");  // ds_write visible
        __builtin_amdgcn_s_barrier();  // raw: no vmcnt(0) drain
    }
#undef LOADA
#undef STAGEB
#undef WRITEA

    // per-row sumsq: 4 consecutive threads share row rA
    ssq += __shfl_xor(ssq, 1, 64);
    ssq += __shfl_xor(ssq, 2, 64);
    if (q == 0) srow[rA] = rsqrtf(ssq*(1.0f/DIM) + 1e-6f);
    __syncthreads();

    #pragma unroll
    for (int mi = 0; mi < 4; mi++)
        #pragma unroll
        for (int ni = 0; ni < 6; ni++) {
            int col_g = wv*96 + ni*16 + lr;
            #pragma unroll
            for (int rr = 0; rr < 4; rr++) {
                int rloc = mi*16 + lg*4 + rr;
                qkv[(size_t)(row0 + rloc)*QKVC + col_g] =
                    (bf16_t)(acc[mi][ni][rr] * srow[rloc]);
            }
        }
}

// ---------- kernel 2: per-(b,chunk) Gram + sumsq partials ----------
__global__ __launch_bounds__(256) void k_stats(const bf16_t* __restrict__ qkv,
    float* __restrict__ stats)
{
    __shared__ bf16_t qk[64*264];   // 64 tokens x 256 (q,k cols) + pad 8
    int bid = blockIdx.x;           // 512 = 8b * 64ch
    int b = bid >> 6, ch = bid & 63;
    int t = threadIdx.x;
    #pragma unroll
    for (int rd = 0; rd < 8; rd++) {
        int tok = (t >> 5) + 8*rd;
        int c8  = (t & 31) * 8;     // cols 0..255 = q,k
        *reinterpret_cast<uint4*>(&qk[tok*264 + c8]) =
            *reinterpret_cast<const uint4*>(
                qkv + ((size_t)b*NTOK + ch*64 + tok)*QKVC + c8);
    }
    __syncthreads();
    int h = t >> 5, s = t & 31, i0 = (s >> 4)*8, j = s & 15;
    float gram[8] = {}, qsq[8] = {}, ksq = 0.f;
    for (int tok = 0; tok < 64; tok++) {
        bf16x8 q8 = *reinterpret_cast<const bf16x8*>(&qk[tok*264 + h*16 + i0]);
        float kf = (float)qk[tok*264 + 128 + h*16 + j];
        ksq += kf*kf;
        #pragma unroll
        for (int m = 0; m < 8; m++) {
            float qf = (float)q8[m];
            gram[m] += qf*kf;
            qsq[m]  += qf*qf;
        }
    }
    float* base = stats + ((size_t)(b*64 + ch)*8 + h)*288;
    #pragma unroll
    for (int m = 0; m < 8; m++) base[(i0 + m)*16 + j] = gram[m];
    if (j == 0) {
        #pragma unroll
        for (int m = 0; m < 8; m++) base[256 + i0 + m] = qsq[m];
    }
    if (s < 16) base[272 + j] = ksq;
}

// ---------- kernel 3: reduce partials, l2-normalize, temperature, softmax ----------
__global__ __launch_bounds__(256) void k_attn(const float* __restrict__ stats,
    const float* __restrict__ temp, float* __restrict__ attn)
{
    int bid = blockIdx.x;           // 64 = 8b * 8h
    int b = bid >> 3, h = bid & 7;
    int t = threadIdx.x, i = t >> 4, j = t & 15;
    float gsum = 0.f, qs = 0.f, ks = 0.f;
    for (int ch = 0; ch < 64; ch++) {
        const float* base = stats + ((size_t)(b*64 + ch)*8 + h)*288;
        gsum += base[i*16 + j];
        qs   += base[256 + i];
        ks   += base[272 + j];
    }
    float et  = expf(temp[h]);
    float sim = gsum * et / (fmaxf(sqrtf(qs), 1e-12f) * fmaxf(sqrtf(ks), 1e-12f));
    float m = sim;
    #pragma unroll
    for (int d = 1; d < 16; d <<= 1) m = fmaxf(m, __shfl_xor(m, d, 16));
    float e = expf(sim - m);
    float ssum = e;
    #pragma unroll
    for (int d = 1; d < 16; d <<= 1) ssum += __shfl_xor(ssum, d, 16);
    attn[((size_t)(b*8 + h)*16 + i)*16 + j] = e / ssum;
}

// ---------- kernel 4: w_eff[b][o][c] = sum_i w_out[o][h*16+i]*attn[b][h][i][j] ----------
__global__ __launch_bounds__(256) void k_weff(const float* __restrict__ attn,
    const float* __restrict__ wout, bf16_t* __restrict__ weff)
{
    __shared__ float at[2048];
    int bid = blockIdx.x;           // 256 = 8b * 32
    int b = bid >> 5, ob = (bid & 31)*32;
    int t = threadIdx.x;
    #pragma unroll
    for (int r = 0; r < 8; r++) at[t + 256*r] = attn[(size_t)b*2048 + t + 256*r];
    __syncthreads();
    int c = t & 127, h = c >> 4, j = c & 15, oo = (t >> 7)*16;
    #pragma unroll
    for (int m = 0; m < 16; m++) {
        int o = ob + oo + m;
        float acc = 0.f;
        #pragma unroll
        for (int i2 = 0; i2 < 16; i2++)
            acc += wout[(size_t)o*INNER + h*16 + i2] * at[(h*16 + i2)*16 + j];
        weff[((size_t)b*DIM + o)*INNER + c] = (bf16_t)acc;
    }
}

// ---------- kernel 5: output GEMM  per b: (4096x128)x(128x1024), fp32 out ----------
__global__ __launch_bounds__(256) void k_out_gemm(const bf16_t* __restrict__ qkv,
    const bf16_t* __restrict__ weff, float* __restrict__ out)
{
    __shared__ bf16_t Al[128*136];
    __shared__ bf16_t Bl[128*136];
    int bid = blockIdx.x;           // 2048 = 8b * 32mt * 8nt
    int b = bid >> 8, rem = bid & 255;
    int mt = rem >> 3, nt = rem & 7;
    int tok0 = mt*128, o0 = nt*128;
    int t = threadIdx.x;
    #pragma unroll
    for (int rd = 0; rd < 8; rd++) {
        int r  = (t >> 4) + 16*rd;
        int c8 = (t & 15) * 8;
        *reinterpret_cast<uint4*>(&Al[r*136 + c8]) =
            *reinterpret_cast<const uint4*>(
                qkv + ((size_t)b*NTOK + tok0 + r)*QKVC + 256 + c8);   // v cols
        *reinterpret_cast<uint4*>(&Bl[r*136 + c8]) =
            *reinterpret_cast<const uint4*>(
                weff + ((size_t)b*DIM + o0 + r)*INNER + c8);
    }
    __syncthreads();
    int w = t >> 6, lane = t & 63, lr = lane & 15, lg = lane >> 4;
    int wr = (w & 1)*64, wc = (w >> 1)*64;
    f32x4 acc[4][4] = {};
    #pragma unroll
    for (int kk = 0; kk < 4; kk++) {
        int kb = kk*32 + lg*8;
        bf16x8 af[4], bfr[4];
        #pragma unroll
        for (int mi = 0; mi < 4; mi++)
            af[mi] = *reinterpret_cast<const bf16x8*>(&Al[(wr + mi*16 + lr)*136 + kb]);
        #pragma unroll
        for (int ni = 0; ni < 4; ni++)
            bfr[ni] = *reinterpret_cast<const bf16x8*>(&Bl[(wc + ni*16 + lr)*136 + kb]);
        #pragma unroll
        for (int mi = 0; mi < 4; mi++)
            #pragma unroll
            for (int ni = 0; ni < 4; ni++)
                acc[mi][ni] = __builtin_amdgcn_mfma_f32_16x16x32_bf16(
                    af[mi], bfr[ni], acc[mi][ni], 0, 0, 0);
    }
    #pragma unroll
    for (int mi = 0; mi < 4; mi++)
        #pragma unroll
        for (int ni = 0; ni < 4; ni++) {
            int col_g = o0 + wc + ni*16 + lr;
            #pragma unroll
            for (int r = 0; r < 4; r++) {
                int row_g = tok0 + wr + mi*16 + lg*4 + r;
                out[((size_t)b*NTOK + row_g)*DIM + col_g] = acc[mi][ni][r];
            }
        }
}

extern "C" void kernel_launch(void* const* d_in, const int* in_sizes, int n_in,
                              void* d_out, int out_size, void* d_ws, size_t ws_size,
                              hipStream_t stream)
{
    const float* x    = (const float*)d_in[0];   // 8*4096*1024
    const float* nw   = (const float*)d_in[1];   // 1024
    const float* wq   = (const float*)d_in[2];   // 384*1024
    const float* temp = (const float*)d_in[3];   // 8
    const float* wout = (const float*)d_in[4];   // 1024*128
    float* out = (float*)d_out;

    char* ws = (char*)d_ws;
    bf16_t* wqb   = (bf16_t*)(ws + OFF_WQ);
    bf16_t* qkv   = (bf16_t*)(ws + OFF_QKV);
    float*  stats = (float*)(ws + OFF_STATS);
    float*  attn  = (float*)(ws + OFF_ATTN);
    bf16_t* weff  = (bf16_t*)(ws + OFF_WEFF);

    k_wconv    <<<384,  256, 0, stream>>>(wq, nw, wqb);
    k_qkv_gemm <<<512,  256, 0, stream>>>(x, wqb, qkv);
    k_stats    <<<512,  256, 0, stream>>>(qkv, stats);
    k_attn     <<<64,   256, 0, stream>>>(stats, temp, attn);
    k_weff     <<<256,  256, 0, stream>>>(attn, wout, weff);
    k_out_gemm <<<2048, 256, 0, stream>>>(qkv, weff, out);
}